// Round 8
// baseline (172.154 us; speedup 1.0000x reference)
//
#include <hip/hip_runtime.h>
#include <math.h>

#define T_LEN 1024
#define VV 512
#define VVh 256
#define BB 64
#define NB 16
#define ANG_STEP 0.006135923151542565f   // 2*pi/1024
#define FADE_S 487
#define FADE_E 537
#define ATL 64

__device__ constexpr int KB[NB] = {1,2,3,4,5,6,7,8,12,16,24,32,48,64,96,128};
// cos/sin(2*pi*k/1024) rotation-step constants
__device__ constexpr float CWT[NB] = {
    0.9999811753f, 0.9999247018f, 0.9998305818f, 0.9996988187f,
    0.9995294175f, 0.9993223846f, 0.9990777278f, 0.9987954562f,
    0.9972904567f, 0.9951847267f, 0.9891765100f, 0.9807852804f,
    0.9569403357f, 0.9238795325f, 0.8314696123f, 0.7071067812f};
__device__ constexpr float SWT[NB] = {
    0.0061358846f, 0.0122715383f, 0.0184067299f, 0.0245412285f,
    0.0306748032f, 0.0368072229f, 0.0429382569f, 0.0490676743f,
    0.0735645636f, 0.0980171403f, 0.1467304745f, 0.1950903220f,
    0.2902846773f, 0.3826834324f, 0.5555702330f, 0.7071067812f};

// ---------------- Kernel 1: partial 16-bin DFT over a t-chunk ----------------
// grid (BB, TC), block 256, thread owns v0=2*tid, v0+1 (VPT=2).
// Rotation recurrence in regs; 8-deep double-buffered prefetch; 3 waves/SIMD.
// Partials: xp[((b*TC + tc)*32 + q)*VV + v], q in [0,16)=re_j, [16,32)=im_j
template<int TLEN>
__global__ __launch_bounds__(256, 3) void k_dft_partial(const float* __restrict__ x,
                                                        float* __restrict__ xpart,
                                                        int tc_count) {
    const int b   = blockIdx.x;
    const int tc  = blockIdx.y;
    const int tid = threadIdx.x;
    const int t0  = tc * TLEN;

    float xr0[NB], xi0[NB], xr1[NB], xi1[NB], c[NB], s[NB];
#pragma unroll
    for (int j = 0; j < NB; ++j) {
        xr0[j] = xi0[j] = xr1[j] = xi1[j] = 0.0f;
        int n0 = (KB[j] * t0) & (T_LEN - 1);
        sincosf(ANG_STEP * (float)n0, &s[j], &c[j]);
    }

    const float2* xrd = (const float2*)(x + ((size_t)b * T_LEN + t0) * VV) + tid;

#define DFT_STEP(AV)                                            \
    do {                                                        \
        _Pragma("unroll")                                       \
        for (int j = 0; j < NB; ++j) {                          \
            xr0[j] = fmaf(AV.x, c[j], xr0[j]);                  \
            xi0[j] = fmaf(-AV.x, s[j], xi0[j]);                 \
            xr1[j] = fmaf(AV.y, c[j], xr1[j]);                  \
            xi1[j] = fmaf(-AV.y, s[j], xi1[j]);                 \
            float cn = fmaf(c[j], CWT[j], -(s[j] * SWT[j]));    \
            float sn = fmaf(s[j], CWT[j], c[j] * SWT[j]);       \
            c[j] = cn; s[j] = sn;                               \
        }                                                       \
    } while (0)

    float2 a0 = xrd[(size_t)0 * VVh];
    float2 a1 = xrd[(size_t)1 * VVh];
    float2 a2 = xrd[(size_t)2 * VVh];
    float2 a3 = xrd[(size_t)3 * VVh];
    float2 a4 = xrd[(size_t)4 * VVh];
    float2 a5 = xrd[(size_t)5 * VVh];
    float2 a6 = xrd[(size_t)6 * VVh];
    float2 a7 = xrd[(size_t)7 * VVh];
#pragma unroll 1
    for (int t = 0; t < TLEN - 8; t += 8) {
        float2 b0 = xrd[(size_t)(t +  8) * VVh];
        float2 b1 = xrd[(size_t)(t +  9) * VVh];
        float2 b2 = xrd[(size_t)(t + 10) * VVh];
        float2 b3 = xrd[(size_t)(t + 11) * VVh];
        float2 b4 = xrd[(size_t)(t + 12) * VVh];
        float2 b5 = xrd[(size_t)(t + 13) * VVh];
        float2 b6 = xrd[(size_t)(t + 14) * VVh];
        float2 b7 = xrd[(size_t)(t + 15) * VVh];
        DFT_STEP(a0); DFT_STEP(a1); DFT_STEP(a2); DFT_STEP(a3);
        DFT_STEP(a4); DFT_STEP(a5); DFT_STEP(a6); DFT_STEP(a7);
        a0 = b0; a1 = b1; a2 = b2; a3 = b3;
        a4 = b4; a5 = b5; a6 = b6; a7 = b7;
    }
    DFT_STEP(a0); DFT_STEP(a1); DFT_STEP(a2); DFT_STEP(a3);
    DFT_STEP(a4); DFT_STEP(a5); DFT_STEP(a6); DFT_STEP(a7);
#undef DFT_STEP

    float2* o = (float2*)(xpart + (size_t)(b * tc_count + tc) * 32 * VV) + tid;
#pragma unroll
    for (int j = 0; j < NB; ++j) {
        o[(size_t)j        * VVh] = make_float2(xr0[j], xr1[j]);
        o[(size_t)(NB + j) * VVh] = make_float2(xi0[j], xi1[j]);
    }
}

// ---------------- Kernel 2: reduce partials, apply gains -> H ----------------
// grid (BB, NB): one j-bin per block (1024 blocks).
// H layout: H[b][q][v], q: [0,16)=He_re, [16,32)=-He_im, [32,48)=Hl_re, [48,64)=-Hl_im
__global__ __launch_bounds__(256) void k_combine(const float* __restrict__ xpart,
                                                 const float* __restrict__ ger,
                                                 const float* __restrict__ gei,
                                                 const float* __restrict__ glr,
                                                 const float* __restrict__ gli,
                                                 float* __restrict__ H, int tc_count) {
    const int b   = blockIdx.x;
    const int j   = blockIdx.y;
    const int tid = threadIdx.x;
    const int v0  = tid * 2;

    float re0 = 0.f, re1 = 0.f, im0 = 0.f, im1 = 0.f;
#pragma unroll 8
    for (int tc = 0; tc < tc_count; ++tc) {
        const float2* p = (const float2*)(xpart + (size_t)(b * tc_count + tc) * 32 * VV) + tid;
        float2 a  = p[(size_t)j        * VVh];
        float2 bb = p[(size_t)(NB + j) * VVh];
        re0 += a.x;  re1 += a.y;
        im0 += bb.x; im1 += bb.y;
    }

    const float scale = 2.0f / (float)T_LEN;
    float er0 = ger[v0 * NB + j],       ei0 = gei[v0 * NB + j];
    float lr0 = glr[v0 * NB + j],       li0 = gli[v0 * NB + j];
    float er1 = ger[(v0 + 1) * NB + j], ei1 = gei[(v0 + 1) * NB + j];
    float lr1 = glr[(v0 + 1) * NB + j], li1 = gli[(v0 + 1) * NB + j];

    float here0 = (re0 * er0 - im0 * ei0) * scale;
    float heim0 = (re0 * ei0 + im0 * er0) * scale;
    float hlre0 = (re0 * lr0 - im0 * li0) * scale;
    float hlim0 = (re0 * li0 + im0 * lr0) * scale;
    float here1 = (re1 * er1 - im1 * ei1) * scale;
    float heim1 = (re1 * ei1 + im1 * er1) * scale;
    float hlre1 = (re1 * lr1 - im1 * li1) * scale;
    float hlim1 = (re1 * li1 + im1 * lr1) * scale;

    float2* o = (float2*)(H + (size_t)b * 64 * VV) + tid;
    o[(size_t)j        * VVh] = make_float2(here0, here1);
    o[(size_t)(16 + j) * VVh] = make_float2(-heim0, -heim1);
    o[(size_t)(32 + j) * VVh] = make_float2(hlre0, hlre1);
    o[(size_t)(48 + j) * VVh] = make_float2(-hlim0, -hlim1);
}

// ---------------- Kernel 3a: pure-early/late tiles (single H set) ----------------
// grid (BB, 14), block 256, VPT=2, recurrence cs, 8-deep prefetch, 3 waves/SIMD.
__global__ __launch_bounds__(256, 3) void k_apply_pure(const float* __restrict__ x,
                                                       const float* __restrict__ H,
                                                       float* __restrict__ out) {
    const int b    = blockIdx.x;
    const int ti   = blockIdx.y;
    const int tid  = threadIdx.x;
    const int tile = (ti < 7) ? ti : ti + 2;
    const int t0   = tile * ATL;
    const int qo   = (ti < 7) ? 0 : 32;

    float hr0[NB], hi0[NB], hr1[NB], hi1[NB], c[NB], s[NB];
    const float2* hp = (const float2*)(H + (size_t)b * 64 * VV) + tid;
#pragma unroll
    for (int j = 0; j < NB; ++j) {
        float2 a  = hp[(size_t)(qo + j)      * VVh]; hr0[j] = a.x;  hr1[j] = a.y;
        float2 bq = hp[(size_t)(qo + 16 + j) * VVh]; hi0[j] = bq.x; hi1[j] = bq.y;
        int n0 = (KB[j] * t0) & (T_LEN - 1);
        sincosf(ANG_STEP * (float)n0, &s[j], &c[j]);
    }

    const float2* xrd = (const float2*)(x + ((size_t)b * T_LEN + t0) * VV) + tid;
    float2*       ow  = (float2*)(out + ((size_t)b * T_LEN + t0) * VV) + tid;

#define APPLY_STEP(U, AV)                                       \
    do {                                                        \
        float s0 = 0.f, s1 = 0.f;                               \
        _Pragma("unroll")                                       \
        for (int j = 0; j < NB; ++j) {                          \
            s0 = fmaf(hr0[j], c[j], s0);                        \
            s0 = fmaf(hi0[j], s[j], s0);                        \
            s1 = fmaf(hr1[j], c[j], s1);                        \
            s1 = fmaf(hi1[j], s[j], s1);                        \
            float cn = fmaf(c[j], CWT[j], -(s[j] * SWT[j]));    \
            float sn = fmaf(s[j], CWT[j], c[j] * SWT[j]);       \
            c[j] = cn; s[j] = sn;                               \
        }                                                       \
        ow[(size_t)(t + U) * VVh] =                             \
            make_float2(AV.x + s0, AV.y + s1);                  \
    } while (0)

    float2 a0 = xrd[(size_t)0 * VVh];
    float2 a1 = xrd[(size_t)1 * VVh];
    float2 a2 = xrd[(size_t)2 * VVh];
    float2 a3 = xrd[(size_t)3 * VVh];
    float2 a4 = xrd[(size_t)4 * VVh];
    float2 a5 = xrd[(size_t)5 * VVh];
    float2 a6 = xrd[(size_t)6 * VVh];
    float2 a7 = xrd[(size_t)7 * VVh];
#pragma unroll 1
    for (int t = 0; t < ATL - 8; t += 8) {
        float2 b0 = xrd[(size_t)(t +  8) * VVh];
        float2 b1 = xrd[(size_t)(t +  9) * VVh];
        float2 b2 = xrd[(size_t)(t + 10) * VVh];
        float2 b3 = xrd[(size_t)(t + 11) * VVh];
        float2 b4 = xrd[(size_t)(t + 12) * VVh];
        float2 b5 = xrd[(size_t)(t + 13) * VVh];
        float2 b6 = xrd[(size_t)(t + 14) * VVh];
        float2 b7 = xrd[(size_t)(t + 15) * VVh];
        APPLY_STEP(0, a0); APPLY_STEP(1, a1); APPLY_STEP(2, a2); APPLY_STEP(3, a3);
        APPLY_STEP(4, a4); APPLY_STEP(5, a5); APPLY_STEP(6, a6); APPLY_STEP(7, a7);
        a0 = b0; a1 = b1; a2 = b2; a3 = b3;
        a4 = b4; a5 = b5; a6 = b6; a7 = b7;
    }
    {
        const int t = ATL - 8;
        APPLY_STEP(0, a0); APPLY_STEP(1, a1); APPLY_STEP(2, a2); APPLY_STEP(3, a3);
        APPLY_STEP(4, a4); APPLY_STEP(5, a5); APPLY_STEP(6, a6); APPLY_STEP(7, a7);
    }
#undef APPLY_STEP
}

// ---------------- Kernel 3b: fade tiles (both H sets), self-built LDS table ----------------
// grid (BB, 2), block 512, thread owns v = tid. Only 2/16 tiles; not critical.
__global__ __launch_bounds__(512) void k_apply_fade(const float* __restrict__ x,
                                                    const float* __restrict__ H,
                                                    float* __restrict__ out) {
    const int b   = blockIdx.x;
    const int tz  = blockIdx.y;
    const int tid = threadIdx.x;
    const int t0  = (7 + tz) * ATL;

    __shared__ float2 tab[ATL][NB];
    for (int i = tid; i < ATL * NB; i += 512) {
        int t = i >> 4, j = i & 15;
        int idx = (KB[j] * (t0 + t)) & (T_LEN - 1);
        float ss, cc; sincosf(ANG_STEP * (float)idx, &ss, &cc);
        tab[t][j] = make_float2(cc, ss);
    }

    float er[NB], ei[NB], lr[NB], li[NB];
    const float* hp = H + (size_t)b * 64 * VV + tid;
#pragma unroll
    for (int j = 0; j < NB; ++j) {
        er[j] = hp[(size_t)j        * VV];
        ei[j] = hp[(size_t)(16 + j) * VV];
        lr[j] = hp[(size_t)(32 + j) * VV];
        li[j] = hp[(size_t)(48 + j) * VV];
    }
    __syncthreads();

    const float* xrd = x + ((size_t)b * T_LEN + t0) * VV + tid;
    float*       ow  = out + ((size_t)b * T_LEN + t0) * VV + tid;

    for (int t = 0; t < ATL; t += 2) {
        float a0 = xrd[(size_t)(t + 0) * VV];
        float a1 = xrd[(size_t)(t + 1) * VV];
#pragma unroll
        for (int u = 0; u < 2; ++u) {
            float av = u ? a1 : a0;
            const int tg = t0 + t + u;
            float se = 0.f, sl = 0.f;
#pragma unroll
            for (int j = 0; j < NB; ++j) {
                float2 cs = tab[t + u][j];
                se = fmaf(er[j], cs.x, se); se = fmaf(ei[j], cs.y, se);
                sl = fmaf(lr[j], cs.x, sl); sl = fmaf(li[j], cs.y, sl);
            }
            float w = (tg < FADE_S) ? 1.0f
                    : ((tg < FADE_E) ? (1.0f - (float)(tg - FADE_S) * (1.0f / 50.0f)) : 0.0f);
            ow[(size_t)(t + u) * VV] = av + fmaf(w, se - sl, sl);
        }
    }
}

extern "C" void kernel_launch(void* const* d_in, const int* in_sizes, int n_in,
                              void* d_out, int out_size, void* d_ws, size_t ws_size,
                              hipStream_t stream) {
    (void)in_sizes; (void)n_in; (void)out_size;
    const float* x   = (const float*)d_in[0];
    const float* ger = (const float*)d_in[1];
    const float* gei = (const float*)d_in[2];
    const float* glr = (const float*)d_in[3];
    const float* gli = (const float*)d_in[4];
    float* out = (float*)d_out;

    // ws layout: partials | H
    const size_t hflts = (size_t)BB * 64 * VV;
    int TC;
    if (((size_t)BB * 8 * 32 * VV + hflts) * sizeof(float) <= ws_size)  TC = 8;
    else                                                                TC = 4;

    float* xpart = (float*)d_ws;
    float* H     = xpart + (size_t)BB * TC * 32 * VV;

    if (TC == 8) k_dft_partial<128><<<dim3(BB, 8), 256, 0, stream>>>(x, xpart, 8);
    else         k_dft_partial<256><<<dim3(BB, 4), 256, 0, stream>>>(x, xpart, 4);

    k_combine<<<dim3(BB, NB), 256, 0, stream>>>(xpart, ger, gei, glr, gli, H, TC);
    k_apply_pure<<<dim3(BB, 14), 256, 0, stream>>>(x, H, out);
    k_apply_fade<<<dim3(BB, 2),  512, 0, stream>>>(x, H, out);
}

// Round 10
// 133.135 us; speedup vs baseline: 1.2931x; 1.2931x over previous
//
#include <hip/hip_runtime.h>
#include <math.h>

#define T_LEN 1024
#define VV 512
#define VVh 256
#define BB 64
#define NB 16
#define ANG_STEP 0.006135923151542565f   // 2*pi/1024
#define FADE_S 487
#define FADE_E 537
#define ATL 64

__device__ constexpr int KB[NB] = {1,2,3,4,5,6,7,8,12,16,24,32,48,64,96,128};

// ---------------- Kernel 1: partial 16-bin DFT over a t-chunk ----------------
// grid (BB, TC), block 256, thread owns v0=2*tid, v0+1 (VPT=2).
// cs from per-block LDS table: 16 broadcast ds_read_b64 (~96cy, LDS pipe) hide
// under 64 fma-inst (128cy, VALU pipe) per wave-t. No rotation VALU overhead.
// Partials: xp[((b*TC + tc)*32 + q)*VV + v], q in [0,16)=re_j, [16,32)=im_j
template<int TLEN>
__global__ __launch_bounds__(256, 2) void k_dft_partial(const float* __restrict__ x,
                                                        float* __restrict__ xpart,
                                                        int tc_count) {
    const int b   = blockIdx.x;
    const int tc  = blockIdx.y;
    const int tid = threadIdx.x;
    const int t0  = tc * TLEN;

    __shared__ float2 tab[TLEN][NB];
    for (int i = tid; i < TLEN * NB; i += 256) {
        int t = i >> 4, j = i & 15;
        int idx = (KB[j] * (t0 + t)) & (T_LEN - 1);
        float ss, cc; sincosf(ANG_STEP * (float)idx, &ss, &cc);
        tab[t][j] = make_float2(cc, ss);
    }
    __syncthreads();

    float xr0[NB], xi0[NB], xr1[NB], xi1[NB];
#pragma unroll
    for (int j = 0; j < NB; ++j) { xr0[j] = xi0[j] = xr1[j] = xi1[j] = 0.0f; }

    const float2* xrd = (const float2*)(x + ((size_t)b * T_LEN + t0) * VV) + tid;

#define DFT_T(TT, AV)                                           \
    do {                                                        \
        _Pragma("unroll")                                       \
        for (int j = 0; j < NB; ++j) {                          \
            float2 cs = tab[(TT)][j];                           \
            xr0[j] = fmaf((AV).x, cs.x, xr0[j]);                \
            xi0[j] = fmaf(-(AV).x, cs.y, xi0[j]);               \
            xr1[j] = fmaf((AV).y, cs.x, xr1[j]);                \
            xi1[j] = fmaf(-(AV).y, cs.y, xi1[j]);               \
        }                                                       \
    } while (0)

    // 4-deep software-pipelined prefetch
    float2 a0 = xrd[(size_t)0 * VVh];
    float2 a1 = xrd[(size_t)1 * VVh];
    float2 a2 = xrd[(size_t)2 * VVh];
    float2 a3 = xrd[(size_t)3 * VVh];
#pragma unroll 1
    for (int t = 0; t < TLEN - 4; t += 4) {
        float2 b0 = xrd[(size_t)(t + 4) * VVh];
        float2 b1 = xrd[(size_t)(t + 5) * VVh];
        float2 b2 = xrd[(size_t)(t + 6) * VVh];
        float2 b3 = xrd[(size_t)(t + 7) * VVh];
        DFT_T(t + 0, a0); DFT_T(t + 1, a1); DFT_T(t + 2, a2); DFT_T(t + 3, a3);
        a0 = b0; a1 = b1; a2 = b2; a3 = b3;
    }
    {
        const int t = TLEN - 4;
        DFT_T(t + 0, a0); DFT_T(t + 1, a1); DFT_T(t + 2, a2); DFT_T(t + 3, a3);
    }
#undef DFT_T

    float2* o = (float2*)(xpart + (size_t)(b * tc_count + tc) * 32 * VV) + tid;
#pragma unroll
    for (int j = 0; j < NB; ++j) {
        o[(size_t)j        * VVh] = make_float2(xr0[j], xr1[j]);
        o[(size_t)(NB + j) * VVh] = make_float2(xi0[j], xi1[j]);
    }
}

// ---------------- Kernel 2: reduce partials, apply gains -> H ----------------
// grid (BB, NB): one j-bin per block (1024 blocks).
// H layout: H[b][q][v], q: [0,16)=He_re, [16,32)=-He_im, [32,48)=Hl_re, [48,64)=-Hl_im
// (ims pre-negated: apply computes hr*cos + hi*sin = Hre*cos - Him*sin.)
__global__ __launch_bounds__(256) void k_combine(const float* __restrict__ xpart,
                                                 const float* __restrict__ ger,
                                                 const float* __restrict__ gei,
                                                 const float* __restrict__ glr,
                                                 const float* __restrict__ gli,
                                                 float* __restrict__ H, int tc_count) {
    const int b   = blockIdx.x;
    const int j   = blockIdx.y;
    const int tid = threadIdx.x;
    const int v0  = tid * 2;

    float re0 = 0.f, re1 = 0.f, im0 = 0.f, im1 = 0.f;
#pragma unroll 8
    for (int tc = 0; tc < tc_count; ++tc) {
        const float2* p = (const float2*)(xpart + (size_t)(b * tc_count + tc) * 32 * VV) + tid;
        float2 a  = p[(size_t)j        * VVh];
        float2 bb = p[(size_t)(NB + j) * VVh];
        re0 += a.x;  re1 += a.y;
        im0 += bb.x; im1 += bb.y;
    }

    const float scale = 2.0f / (float)T_LEN;
    float er0 = ger[v0 * NB + j],       ei0 = gei[v0 * NB + j];
    float lr0 = glr[v0 * NB + j],       li0 = gli[v0 * NB + j];
    float er1 = ger[(v0 + 1) * NB + j], ei1 = gei[(v0 + 1) * NB + j];
    float lr1 = glr[(v0 + 1) * NB + j], li1 = gli[(v0 + 1) * NB + j];

    float here0 = (re0 * er0 - im0 * ei0) * scale;
    float heim0 = (re0 * ei0 + im0 * er0) * scale;
    float hlre0 = (re0 * lr0 - im0 * li0) * scale;
    float hlim0 = (re0 * li0 + im0 * lr0) * scale;
    float here1 = (re1 * er1 - im1 * ei1) * scale;
    float heim1 = (re1 * ei1 + im1 * er1) * scale;
    float hlre1 = (re1 * lr1 - im1 * li1) * scale;
    float hlim1 = (re1 * li1 + im1 * lr1) * scale;

    float2* o = (float2*)(H + (size_t)b * 64 * VV) + tid;
    o[(size_t)j        * VVh] = make_float2(here0, here1);
    o[(size_t)(16 + j) * VVh] = make_float2(-heim0, -heim1);
    o[(size_t)(32 + j) * VVh] = make_float2(hlre0, hlre1);
    o[(size_t)(48 + j) * VVh] = make_float2(-hlim0, -hlim1);
}

// ---------------- Kernel 3a: pure-early/late tiles (single H set) ----------------
// grid (BB, 14), block 256, VPT=2, LDS cs table, 4-deep prefetch.
__global__ __launch_bounds__(256, 2) void k_apply_pure(const float* __restrict__ x,
                                                       const float* __restrict__ H,
                                                       float* __restrict__ out) {
    const int b    = blockIdx.x;
    const int ti   = blockIdx.y;
    const int tid  = threadIdx.x;
    const int tile = (ti < 7) ? ti : ti + 2;
    const int t0   = tile * ATL;
    const int qo   = (ti < 7) ? 0 : 32;

    __shared__ float2 tab[ATL][NB];
    for (int i = tid; i < ATL * NB; i += 256) {
        int t = i >> 4, j = i & 15;
        int idx = (KB[j] * (t0 + t)) & (T_LEN - 1);
        float ss, cc; sincosf(ANG_STEP * (float)idx, &ss, &cc);
        tab[t][j] = make_float2(cc, ss);
    }

    float hr0[NB], hi0[NB], hr1[NB], hi1[NB];
    const float2* hp = (const float2*)(H + (size_t)b * 64 * VV) + tid;
#pragma unroll
    for (int j = 0; j < NB; ++j) {
        float2 a  = hp[(size_t)(qo + j)      * VVh]; hr0[j] = a.x;  hr1[j] = a.y;
        float2 bq = hp[(size_t)(qo + 16 + j) * VVh]; hi0[j] = bq.x; hi1[j] = bq.y;
    }
    __syncthreads();

    const float2* xrd = (const float2*)(x + ((size_t)b * T_LEN + t0) * VV) + tid;
    float2*       ow  = (float2*)(out + ((size_t)b * T_LEN + t0) * VV) + tid;

#define APPLY_T(TT, AV)                                         \
    do {                                                        \
        float s0 = 0.f, s1 = 0.f;                               \
        _Pragma("unroll")                                       \
        for (int j = 0; j < NB; ++j) {                          \
            float2 cs = tab[(TT)][j];                           \
            s0 = fmaf(hr0[j], cs.x, s0);                        \
            s0 = fmaf(hi0[j], cs.y, s0);                        \
            s1 = fmaf(hr1[j], cs.x, s1);                        \
            s1 = fmaf(hi1[j], cs.y, s1);                        \
        }                                                       \
        ow[(size_t)(TT) * VVh] =                                \
            make_float2((AV).x + s0, (AV).y + s1);              \
    } while (0)

    float2 a0 = xrd[(size_t)0 * VVh];
    float2 a1 = xrd[(size_t)1 * VVh];
    float2 a2 = xrd[(size_t)2 * VVh];
    float2 a3 = xrd[(size_t)3 * VVh];
#pragma unroll 1
    for (int t = 0; t < ATL - 4; t += 4) {
        float2 b0 = xrd[(size_t)(t + 4) * VVh];
        float2 b1 = xrd[(size_t)(t + 5) * VVh];
        float2 b2 = xrd[(size_t)(t + 6) * VVh];
        float2 b3 = xrd[(size_t)(t + 7) * VVh];
        APPLY_T(t + 0, a0); APPLY_T(t + 1, a1); APPLY_T(t + 2, a2); APPLY_T(t + 3, a3);
        a0 = b0; a1 = b1; a2 = b2; a3 = b3;
    }
    {
        const int t = ATL - 4;
        APPLY_T(t + 0, a0); APPLY_T(t + 1, a1); APPLY_T(t + 2, a2); APPLY_T(t + 3, a3);
    }
#undef APPLY_T
}

// ---------------- Kernel 3b: fade tiles (both H sets), LDS table ----------------
// grid (BB, 2), block 512, thread owns v = tid. Only 2/16 tiles; not critical.
__global__ __launch_bounds__(512) void k_apply_fade(const float* __restrict__ x,
                                                    const float* __restrict__ H,
                                                    float* __restrict__ out) {
    const int b   = blockIdx.x;
    const int tz  = blockIdx.y;
    const int tid = threadIdx.x;
    const int t0  = (7 + tz) * ATL;

    __shared__ float2 tab[ATL][NB];
    for (int i = tid; i < ATL * NB; i += 512) {
        int t = i >> 4, j = i & 15;
        int idx = (KB[j] * (t0 + t)) & (T_LEN - 1);
        float ss, cc; sincosf(ANG_STEP * (float)idx, &ss, &cc);
        tab[t][j] = make_float2(cc, ss);
    }

    float er[NB], ei[NB], lr[NB], li[NB];
    const float* hp = H + (size_t)b * 64 * VV + tid;
#pragma unroll
    for (int j = 0; j < NB; ++j) {
        er[j] = hp[(size_t)j        * VV];
        ei[j] = hp[(size_t)(16 + j) * VV];
        lr[j] = hp[(size_t)(32 + j) * VV];
        li[j] = hp[(size_t)(48 + j) * VV];
    }
    __syncthreads();

    const float* xrd = x + ((size_t)b * T_LEN + t0) * VV + tid;
    float*       ow  = out + ((size_t)b * T_LEN + t0) * VV + tid;

    for (int t = 0; t < ATL; t += 2) {
        float a0 = xrd[(size_t)(t + 0) * VV];
        float a1 = xrd[(size_t)(t + 1) * VV];
#pragma unroll
        for (int u = 0; u < 2; ++u) {
            float av = u ? a1 : a0;
            const int tg = t0 + t + u;
            float se = 0.f, sl = 0.f;
#pragma unroll
            for (int j = 0; j < NB; ++j) {
                float2 cs = tab[t + u][j];
                se = fmaf(er[j], cs.x, se); se = fmaf(ei[j], cs.y, se);
                sl = fmaf(lr[j], cs.x, sl); sl = fmaf(li[j], cs.y, sl);
            }
            float w = (tg < FADE_S) ? 1.0f
                    : ((tg < FADE_E) ? (1.0f - (float)(tg - FADE_S) * (1.0f / 50.0f)) : 0.0f);
            ow[(size_t)(t + u) * VV] = av + fmaf(w, se - sl, sl);
        }
    }
}

extern "C" void kernel_launch(void* const* d_in, const int* in_sizes, int n_in,
                              void* d_out, int out_size, void* d_ws, size_t ws_size,
                              hipStream_t stream) {
    (void)in_sizes; (void)n_in; (void)out_size;
    const float* x   = (const float*)d_in[0];
    const float* ger = (const float*)d_in[1];
    const float* gei = (const float*)d_in[2];
    const float* glr = (const float*)d_in[3];
    const float* gli = (const float*)d_in[4];
    float* out = (float*)d_out;

    // ws layout: partials | H
    const size_t hflts = (size_t)BB * 64 * VV;
    int TC;
    if (((size_t)BB * 8 * 32 * VV + hflts) * sizeof(float) <= ws_size)  TC = 8;
    else                                                                TC = 4;

    float* xpart = (float*)d_ws;
    float* H     = xpart + (size_t)BB * TC * 32 * VV;

    if (TC == 8) k_dft_partial<128><<<dim3(BB, 8), 256, 0, stream>>>(x, xpart, 8);
    else         k_dft_partial<256><<<dim3(BB, 4), 256, 0, stream>>>(x, xpart, 4);

    k_combine<<<dim3(BB, NB), 256, 0, stream>>>(xpart, ger, gei, glr, gli, H, TC);
    k_apply_pure<<<dim3(BB, 14), 256, 0, stream>>>(x, H, out);
    k_apply_fade<<<dim3(BB, 2),  512, 0, stream>>>(x, H, out);
}

// Round 12
// 115.421 us; speedup vs baseline: 1.4915x; 1.1535x over previous
//
#include <hip/hip_runtime.h>
#include <math.h>

#define T_LEN 1024
#define VV 512
#define VVh 256
#define BB 64
#define NB 16
#define ANG_STEP 0.006135923151542565f   // 2*pi/1024
#define FADE_S 487
#define FADE_E 537
#define ATL 64

typedef float v2f __attribute__((ext_vector_type(2)));   // native vec for nontemporal builtin

__device__ constexpr int KB[NB] = {1,2,3,4,5,6,7,8,12,16,24,32,48,64,96,128};

// ---------------- Kernel 1: partial 16-bin DFT over a t-chunk ----------------
// grid (BB, TC), block 256, thread owns v0=2*tid, v0+1 (VPT=2).
// cs from per-block LDS table (broadcast ds_read_b64 on LDS pipe hides under
// 64 fma-inst/t on VALU pipe). 8-deep prefetch: ~1280 cyc compute cover > ~900
// cyc HBM latency.
// Partials: xp[((b*TC + tc)*32 + q)*VV + v], q in [0,16)=re_j, [16,32)=im_j
template<int TLEN>
__global__ __launch_bounds__(256, 2) void k_dft_partial(const float* __restrict__ x,
                                                        float* __restrict__ xpart,
                                                        int tc_count) {
    const int b   = blockIdx.x;
    const int tc  = blockIdx.y;
    const int tid = threadIdx.x;
    const int t0  = tc * TLEN;

    __shared__ float2 tab[TLEN][NB];
    for (int i = tid; i < TLEN * NB; i += 256) {
        int t = i >> 4, j = i & 15;
        int idx = (KB[j] * (t0 + t)) & (T_LEN - 1);
        float ss, cc; sincosf(ANG_STEP * (float)idx, &ss, &cc);
        tab[t][j] = make_float2(cc, ss);
    }
    __syncthreads();

    float xr0[NB], xi0[NB], xr1[NB], xi1[NB];
#pragma unroll
    for (int j = 0; j < NB; ++j) { xr0[j] = xi0[j] = xr1[j] = xi1[j] = 0.0f; }

    const float2* xrd = (const float2*)(x + ((size_t)b * T_LEN + t0) * VV) + tid;

#define DFT_T(TT, AV)                                           \
    do {                                                        \
        _Pragma("unroll")                                       \
        for (int j = 0; j < NB; ++j) {                          \
            float2 cs = tab[(TT)][j];                           \
            xr0[j] = fmaf((AV).x, cs.x, xr0[j]);                \
            xi0[j] = fmaf(-(AV).x, cs.y, xi0[j]);               \
            xr1[j] = fmaf((AV).y, cs.x, xr1[j]);                \
            xi1[j] = fmaf(-(AV).y, cs.y, xi1[j]);               \
        }                                                       \
    } while (0)

    // 8-deep software-pipelined prefetch
    float2 a0 = xrd[(size_t)0 * VVh];
    float2 a1 = xrd[(size_t)1 * VVh];
    float2 a2 = xrd[(size_t)2 * VVh];
    float2 a3 = xrd[(size_t)3 * VVh];
    float2 a4 = xrd[(size_t)4 * VVh];
    float2 a5 = xrd[(size_t)5 * VVh];
    float2 a6 = xrd[(size_t)6 * VVh];
    float2 a7 = xrd[(size_t)7 * VVh];
#pragma unroll 1
    for (int t = 0; t < TLEN - 8; t += 8) {
        float2 b0 = xrd[(size_t)(t +  8) * VVh];
        float2 b1 = xrd[(size_t)(t +  9) * VVh];
        float2 b2 = xrd[(size_t)(t + 10) * VVh];
        float2 b3 = xrd[(size_t)(t + 11) * VVh];
        float2 b4 = xrd[(size_t)(t + 12) * VVh];
        float2 b5 = xrd[(size_t)(t + 13) * VVh];
        float2 b6 = xrd[(size_t)(t + 14) * VVh];
        float2 b7 = xrd[(size_t)(t + 15) * VVh];
        DFT_T(t + 0, a0); DFT_T(t + 1, a1); DFT_T(t + 2, a2); DFT_T(t + 3, a3);
        DFT_T(t + 4, a4); DFT_T(t + 5, a5); DFT_T(t + 6, a6); DFT_T(t + 7, a7);
        a0 = b0; a1 = b1; a2 = b2; a3 = b3;
        a4 = b4; a5 = b5; a6 = b6; a7 = b7;
    }
    {
        const int t = TLEN - 8;
        DFT_T(t + 0, a0); DFT_T(t + 1, a1); DFT_T(t + 2, a2); DFT_T(t + 3, a3);
        DFT_T(t + 4, a4); DFT_T(t + 5, a5); DFT_T(t + 6, a6); DFT_T(t + 7, a7);
    }
#undef DFT_T

    float2* o = (float2*)(xpart + (size_t)(b * tc_count + tc) * 32 * VV) + tid;
#pragma unroll
    for (int j = 0; j < NB; ++j) {
        o[(size_t)j        * VVh] = make_float2(xr0[j], xr1[j]);
        o[(size_t)(NB + j) * VVh] = make_float2(xi0[j], xi1[j]);
    }
}

// ---------------- Kernel 2: reduce partials, apply gains -> H ----------------
// grid (BB, NB): one j-bin per block (1024 blocks).
// H layout: H[b][q][v], q: [0,16)=He_re, [16,32)=-He_im, [32,48)=Hl_re, [48,64)=-Hl_im
// (ims pre-negated: apply computes hr*cos + hi*sin = Hre*cos - Him*sin.)
__global__ __launch_bounds__(256) void k_combine(const float* __restrict__ xpart,
                                                 const float* __restrict__ ger,
                                                 const float* __restrict__ gei,
                                                 const float* __restrict__ glr,
                                                 const float* __restrict__ gli,
                                                 float* __restrict__ H, int tc_count) {
    const int b   = blockIdx.x;
    const int j   = blockIdx.y;
    const int tid = threadIdx.x;
    const int v0  = tid * 2;

    float re0 = 0.f, re1 = 0.f, im0 = 0.f, im1 = 0.f;
#pragma unroll 8
    for (int tc = 0; tc < tc_count; ++tc) {
        const float2* p = (const float2*)(xpart + (size_t)(b * tc_count + tc) * 32 * VV) + tid;
        float2 a  = p[(size_t)j        * VVh];
        float2 bb = p[(size_t)(NB + j) * VVh];
        re0 += a.x;  re1 += a.y;
        im0 += bb.x; im1 += bb.y;
    }

    const float scale = 2.0f / (float)T_LEN;
    float er0 = ger[v0 * NB + j],       ei0 = gei[v0 * NB + j];
    float lr0 = glr[v0 * NB + j],       li0 = gli[v0 * NB + j];
    float er1 = ger[(v0 + 1) * NB + j], ei1 = gei[(v0 + 1) * NB + j];
    float lr1 = glr[(v0 + 1) * NB + j], li1 = gli[(v0 + 1) * NB + j];

    float here0 = (re0 * er0 - im0 * ei0) * scale;
    float heim0 = (re0 * ei0 + im0 * er0) * scale;
    float hlre0 = (re0 * lr0 - im0 * li0) * scale;
    float hlim0 = (re0 * li0 + im0 * lr0) * scale;
    float here1 = (re1 * er1 - im1 * ei1) * scale;
    float heim1 = (re1 * ei1 + im1 * er1) * scale;
    float hlre1 = (re1 * lr1 - im1 * li1) * scale;
    float hlim1 = (re1 * li1 + im1 * lr1) * scale;

    float2* o = (float2*)(H + (size_t)b * 64 * VV) + tid;
    o[(size_t)j        * VVh] = make_float2(here0, here1);
    o[(size_t)(16 + j) * VVh] = make_float2(-heim0, -heim1);
    o[(size_t)(32 + j) * VVh] = make_float2(hlre0, hlre1);
    o[(size_t)(48 + j) * VVh] = make_float2(-hlim0, -hlim1);
}

// ---------------- Kernel 3: uniform apply, single H set per tile ----------------
// grid (BB, 16), block 256, VPT=2. He for tiles 0..7, Hl for 8..15.
// Fade rows 487..536 get overwritten by k_fixup afterwards.
// Non-temporal stores: out is write-only; keep L2/L3 for x.
__global__ __launch_bounds__(256, 2) void k_apply(const float* __restrict__ x,
                                                  const float* __restrict__ H,
                                                  float* __restrict__ out) {
    const int b    = blockIdx.x;
    const int tile = blockIdx.y;
    const int tid  = threadIdx.x;
    const int t0   = tile * ATL;
    const int qo   = (tile < 8) ? 0 : 32;

    __shared__ float2 tab[ATL][NB];
    for (int i = tid; i < ATL * NB; i += 256) {
        int t = i >> 4, j = i & 15;
        int idx = (KB[j] * (t0 + t)) & (T_LEN - 1);
        float ss, cc; sincosf(ANG_STEP * (float)idx, &ss, &cc);
        tab[t][j] = make_float2(cc, ss);
    }

    float hr0[NB], hi0[NB], hr1[NB], hi1[NB];
    const float2* hp = (const float2*)(H + (size_t)b * 64 * VV) + tid;
#pragma unroll
    for (int j = 0; j < NB; ++j) {
        float2 a  = hp[(size_t)(qo + j)      * VVh]; hr0[j] = a.x;  hr1[j] = a.y;
        float2 bq = hp[(size_t)(qo + 16 + j) * VVh]; hi0[j] = bq.x; hi1[j] = bq.y;
    }
    __syncthreads();

    const float2* xrd = (const float2*)(x + ((size_t)b * T_LEN + t0) * VV) + tid;
    v2f*          ow  = (v2f*)(out + ((size_t)b * T_LEN + t0) * VV) + tid;

#define APPLY_T(TT, AV)                                         \
    do {                                                        \
        float s0 = 0.f, s1 = 0.f;                               \
        _Pragma("unroll")                                       \
        for (int j = 0; j < NB; ++j) {                          \
            float2 cs = tab[(TT)][j];                           \
            s0 = fmaf(hr0[j], cs.x, s0);                        \
            s0 = fmaf(hi0[j], cs.y, s0);                        \
            s1 = fmaf(hr1[j], cs.x, s1);                        \
            s1 = fmaf(hi1[j], cs.y, s1);                        \
        }                                                       \
        v2f ov; ov.x = (AV).x + s0; ov.y = (AV).y + s1;         \
        __builtin_nontemporal_store(ov,                         \
            &ow[(size_t)(TT) * VVh]);                           \
    } while (0)

    float2 a0 = xrd[(size_t)0 * VVh];
    float2 a1 = xrd[(size_t)1 * VVh];
    float2 a2 = xrd[(size_t)2 * VVh];
    float2 a3 = xrd[(size_t)3 * VVh];
    float2 a4 = xrd[(size_t)4 * VVh];
    float2 a5 = xrd[(size_t)5 * VVh];
    float2 a6 = xrd[(size_t)6 * VVh];
    float2 a7 = xrd[(size_t)7 * VVh];
#pragma unroll 1
    for (int t = 0; t < ATL - 8; t += 8) {
        float2 b0 = xrd[(size_t)(t +  8) * VVh];
        float2 b1 = xrd[(size_t)(t +  9) * VVh];
        float2 b2 = xrd[(size_t)(t + 10) * VVh];
        float2 b3 = xrd[(size_t)(t + 11) * VVh];
        float2 b4 = xrd[(size_t)(t + 12) * VVh];
        float2 b5 = xrd[(size_t)(t + 13) * VVh];
        float2 b6 = xrd[(size_t)(t + 14) * VVh];
        float2 b7 = xrd[(size_t)(t + 15) * VVh];
        APPLY_T(t + 0, a0); APPLY_T(t + 1, a1); APPLY_T(t + 2, a2); APPLY_T(t + 3, a3);
        APPLY_T(t + 4, a4); APPLY_T(t + 5, a5); APPLY_T(t + 6, a6); APPLY_T(t + 7, a7);
        a0 = b0; a1 = b1; a2 = b2; a3 = b3;
        a4 = b4; a5 = b5; a6 = b6; a7 = b7;
    }
    {
        const int t = ATL - 8;
        APPLY_T(t + 0, a0); APPLY_T(t + 1, a1); APPLY_T(t + 2, a2); APPLY_T(t + 3, a3);
        APPLY_T(t + 4, a4); APPLY_T(t + 5, a5); APPLY_T(t + 6, a6); APPLY_T(t + 7, a7);
    }
#undef APPLY_T
}

// ---------------- Kernel 4: fade fixup, rows 487..536 only ----------------
// grid (BB, 2), block 512, thread owns v = tid. tz=0 -> rows 487..511,
// tz=1 -> rows 512..536. Recomputes the exact dual-H crossfade formula.
__global__ __launch_bounds__(512) void k_fixup(const float* __restrict__ x,
                                               const float* __restrict__ H,
                                               float* __restrict__ out) {
    const int b   = blockIdx.x;
    const int tz  = blockIdx.y;
    const int tid = threadIdx.x;
    const int ts  = tz ? 512 : FADE_S;        // start row
    const int te  = tz ? FADE_E : 512;        // end row (exclusive)
    const int nt  = te - ts;                   // 25 rows each

    __shared__ float2 tab[32][NB];             // up to 25 rows used
    for (int i = tid; i < nt * NB; i += 512) {
        int t = i >> 4, j = i & 15;
        int idx = (KB[j] * (ts + t)) & (T_LEN - 1);
        float ss, cc; sincosf(ANG_STEP * (float)idx, &ss, &cc);
        tab[t][j] = make_float2(cc, ss);
    }

    float er[NB], ei[NB], lr[NB], li[NB];
    const float* hp = H + (size_t)b * 64 * VV + tid;
#pragma unroll
    for (int j = 0; j < NB; ++j) {
        er[j] = hp[(size_t)j        * VV];
        ei[j] = hp[(size_t)(16 + j) * VV];
        lr[j] = hp[(size_t)(32 + j) * VV];
        li[j] = hp[(size_t)(48 + j) * VV];
    }
    __syncthreads();

    const float* xrd = x + ((size_t)b * T_LEN + ts) * VV + tid;
    float*       ow  = out + ((size_t)b * T_LEN + ts) * VV + tid;

    for (int t = 0; t < nt; ++t) {
        float av = xrd[(size_t)t * VV];
        const int tg = ts + t;
        float se = 0.f, sl = 0.f;
#pragma unroll
        for (int j = 0; j < NB; ++j) {
            float2 cs = tab[t][j];
            se = fmaf(er[j], cs.x, se); se = fmaf(ei[j], cs.y, se);
            sl = fmaf(lr[j], cs.x, sl); sl = fmaf(li[j], cs.y, sl);
        }
        float w = 1.0f - (float)(tg - FADE_S) * (1.0f / 50.0f);
        ow[(size_t)t * VV] = av + fmaf(w, se - sl, sl);
    }
}

extern "C" void kernel_launch(void* const* d_in, const int* in_sizes, int n_in,
                              void* d_out, int out_size, void* d_ws, size_t ws_size,
                              hipStream_t stream) {
    (void)in_sizes; (void)n_in; (void)out_size;
    const float* x   = (const float*)d_in[0];
    const float* ger = (const float*)d_in[1];
    const float* gei = (const float*)d_in[2];
    const float* glr = (const float*)d_in[3];
    const float* gli = (const float*)d_in[4];
    float* out = (float*)d_out;

    // ws layout: partials | H
    const size_t hflts = (size_t)BB * 64 * VV;
    int TC;
    if (((size_t)BB * 8 * 32 * VV + hflts) * sizeof(float) <= ws_size)  TC = 8;
    else                                                                TC = 4;

    float* xpart = (float*)d_ws;
    float* H     = xpart + (size_t)BB * TC * 32 * VV;

    if (TC == 8) k_dft_partial<128><<<dim3(BB, 8), 256, 0, stream>>>(x, xpart, 8);
    else         k_dft_partial<256><<<dim3(BB, 4), 256, 0, stream>>>(x, xpart, 4);

    k_combine<<<dim3(BB, NB), 256, 0, stream>>>(xpart, ger, gei, glr, gli, H, TC);
    k_apply<<<dim3(BB, 16), 256, 0, stream>>>(x, H, out);
    k_fixup<<<dim3(BB, 2), 512, 0, stream>>>(x, H, out);
}